// Round 1
// baseline (337.669 us; speedup 1.0000x reference)
//
#include <hip/hip_runtime.h>
#include <math.h>

// Problem constants (from setup_inputs): B=8, J=4, N=4, M=16, K=3, D=32768
constexpr int B_ = 8;
constexpr int J_ = 4;
constexpr int N_ = 4;
constexpr int M_ = 16;
constexpr int K_ = 3;
constexpr int D_ = 32768;
constexpr float EPS_ = 1e-8f;
constexpr float TEMP_INV = 2.0f;   // 1/TEMP, TEMP=0.5

// ---------------------------------------------------------------------------
// Kernel 1: pos logits. One block per (b,k) pair (24 blocks).
// pos[b,k] = dot(x,xp)/max(|x||xp|,eps) / TEMP ;  also store |x| for reuse.
// ---------------------------------------------------------------------------
__global__ __launch_bounds__(256) void pos_kernel(
    const float* __restrict__ fmaps, const float* __restrict__ fmaps_pos,
    float* __restrict__ pos_out, float* __restrict__ nx_out) {
  const int idx = blockIdx.x;                 // b*K + k
  const int b = idx / K_, k = idx % K_;
  const size_t base = (((size_t)b * J_ + (J_ - 1)) * K_ + k) * (size_t)D_;
  const float4* __restrict__ x  = (const float4*)(fmaps + base);
  const float4* __restrict__ xp = (const float4*)(fmaps_pos + base);

  float dot = 0.f, nx = 0.f, np = 0.f;
  for (int i = threadIdx.x; i < D_ / 4; i += 256) {
    float4 a = x[i];
    float4 c = xp[i];
    dot += a.x * c.x + a.y * c.y + a.z * c.z + a.w * c.w;
    nx  += a.x * a.x + a.y * a.y + a.z * a.z + a.w * a.w;
    np  += c.x * c.x + c.y * c.y + c.z * c.z + c.w * c.w;
  }
  // wave64 shuffle reduce
  for (int off = 32; off > 0; off >>= 1) {
    dot += __shfl_down(dot, off, 64);
    nx  += __shfl_down(nx,  off, 64);
    np  += __shfl_down(np,  off, 64);
  }
  __shared__ float s[3][4];
  const int wid = threadIdx.x >> 6, lane = threadIdx.x & 63;
  if (lane == 0) { s[0][wid] = dot; s[1][wid] = nx; s[2][wid] = np; }
  __syncthreads();
  if (threadIdx.x == 0) {
    dot = s[0][0] + s[0][1] + s[0][2] + s[0][3];
    nx  = s[1][0] + s[1][1] + s[1][2] + s[1][3];
    np  = s[2][0] + s[2][1] + s[2][2] + s[2][3];
    const float nxs = sqrtf(nx);
    nx_out[idx]  = nxs;
    pos_out[idx] = dot / fmaxf(nxs * sqrtf(np), EPS_) * TEMP_INV;
  }
}

// ---------------------------------------------------------------------------
// Kernel 2: neg logits. One block per (b,n,m,k) vector (1536 blocks).
// neg[b,n,m,k] = dot(x[b,k], v)/max(|x||v|,eps) / TEMP
// fmaps_neg is laid out (B,N,M,K,D) so blockIdx.x * D indexes the vector.
// ---------------------------------------------------------------------------
__global__ __launch_bounds__(256) void neg_kernel(
    const float* __restrict__ fmaps, const float* __restrict__ fmaps_neg,
    const float* __restrict__ nx_in, float* __restrict__ neg_out) {
  const int idx = blockIdx.x;                 // ((b*N + n)*M + m)*K + k
  const int k = idx % K_;
  const int b = idx / (N_ * M_ * K_);
  const size_t xbase = (((size_t)b * J_ + (J_ - 1)) * K_ + k) * (size_t)D_;
  const float4* __restrict__ x = (const float4*)(fmaps + xbase);
  const float4* __restrict__ v = (const float4*)(fmaps_neg + (size_t)idx * D_);

  float dot = 0.f, nv = 0.f;
  for (int i = threadIdx.x; i < D_ / 4; i += 256) {
    float4 a = x[i];
    float4 c = v[i];
    dot += a.x * c.x + a.y * c.y + a.z * c.z + a.w * c.w;
    nv  += c.x * c.x + c.y * c.y + c.z * c.z + c.w * c.w;
  }
  for (int off = 32; off > 0; off >>= 1) {
    dot += __shfl_down(dot, off, 64);
    nv  += __shfl_down(nv,  off, 64);
  }
  __shared__ float s[2][4];
  const int wid = threadIdx.x >> 6, lane = threadIdx.x & 63;
  if (lane == 0) { s[0][wid] = dot; s[1][wid] = nv; }
  __syncthreads();
  if (threadIdx.x == 0) {
    dot = s[0][0] + s[0][1] + s[0][2] + s[0][3];
    nv  = s[1][0] + s[1][1] + s[1][2] + s[1][3];
    const float nxv = nx_in[b * K_ + k];
    neg_out[idx] = dot / fmaxf(nxv * sqrtf(nv), EPS_) * TEMP_INV;
  }
}

// ---------------------------------------------------------------------------
// Kernel 3: masked logsumexp + final sum. Single block, one wave.
// Threads 0..23 each own one (b,k); reduce over the 65 candidates, then
// wave-reduce the 24 (lse - pos) contributions and write scalar / (2B).
// ---------------------------------------------------------------------------
__global__ __launch_bounds__(64) void lse_kernel(
    const float* __restrict__ pos_in, const float* __restrict__ neg_in,
    const int* __restrict__ gt_labels, const int* __restrict__ gt_label_negs,
    float* __restrict__ out) {
  const int t = threadIdx.x;
  float contrib = 0.f;
  if (t < B_ * K_) {
    const int b = t / K_, k = t % K_;
    const int lbl = gt_labels[b * J_ + (J_ - 1)];
    const float p = pos_in[t];
    float mx = p;
    for (int i = 0; i < N_ * M_; ++i) {
      if (gt_label_negs[b * N_ * M_ + i] == lbl) {
        mx = fmaxf(mx, neg_in[((size_t)b * N_ * M_ + i) * K_ + k]);
      }
    }
    float ssum = expf(p - mx);
    for (int i = 0; i < N_ * M_; ++i) {
      if (gt_label_negs[b * N_ * M_ + i] == lbl) {
        ssum += expf(neg_in[((size_t)b * N_ * M_ + i) * K_ + k] - mx);
      }
    }
    contrib = (mx + logf(ssum)) - p;
  }
  for (int off = 32; off > 0; off >>= 1) contrib += __shfl_down(contrib, off, 64);
  if (t == 0) out[0] = contrib / (2.0f * (float)B_);
}

// ---------------------------------------------------------------------------
extern "C" void kernel_launch(void* const* d_in, const int* in_sizes, int n_in,
                              void* d_out, int out_size, void* d_ws, size_t ws_size,
                              hipStream_t stream) {
  const float* fmaps         = (const float*)d_in[0];
  const float* fmaps_pos     = (const float*)d_in[1];
  const float* fmaps_neg     = (const float*)d_in[2];
  const int*   gt_labels     = (const int*)d_in[3];
  const int*   gt_label_negs = (const int*)d_in[4];
  float* out = (float*)d_out;

  // workspace layout (floats): [0,24) pos logits | [24,48) |x| | [48,48+1536) neg logits
  float* ws      = (float*)d_ws;
  float* pos_ws  = ws;
  float* nx_ws   = ws + B_ * K_;
  float* neg_ws  = ws + 2 * B_ * K_;

  pos_kernel<<<B_ * K_, 256, 0, stream>>>(fmaps, fmaps_pos, pos_ws, nx_ws);
  neg_kernel<<<B_ * N_ * M_ * K_, 256, 0, stream>>>(fmaps, fmaps_neg, nx_ws, neg_ws);
  lse_kernel<<<1, 64, 0, stream>>>(pos_ws, neg_ws, gt_labels, gt_label_negs, out);
}

// Round 2
// 319.757 us; speedup vs baseline: 1.0560x; 1.0560x over previous
//
#include <hip/hip_runtime.h>
#include <math.h>

// Problem constants (from setup_inputs): B=8, J=4, N=4, M=16, K=3, D=32768
constexpr int B_ = 8;
constexpr int J_ = 4;
constexpr int N_ = 4;
constexpr int M_ = 16;
constexpr int K_ = 3;
constexpr int D_ = 32768;
constexpr float EPS_ = 1e-8f;
constexpr float TEMP_INV = 2.0f;   // 1/TEMP, TEMP=0.5

constexpr int NEG_BLOCKS = B_ * N_ * M_ * K_;  // 1536
constexpr int POS_BLOCKS = B_ * K_;            // 24

// ---------------------------------------------------------------------------
// Fused kernel: blocks [0,1536) compute neg logits, [1536,1560) pos logits.
// neg blocks compute |x| themselves from the x stream they already load,
// removing the pos->neg dependency (kernels previously serialized on nx_ws).
// ---------------------------------------------------------------------------
__global__ __launch_bounds__(256) void logits_kernel(
    const float* __restrict__ fmaps, const float* __restrict__ fmaps_pos,
    const float* __restrict__ fmaps_neg,
    float* __restrict__ pos_out, float* __restrict__ neg_out) {
  __shared__ float s[3][4];
  const int wid = threadIdx.x >> 6, lane = threadIdx.x & 63;

  if (blockIdx.x < NEG_BLOCKS) {
    // ---- negative logit: idx = ((b*N + n)*M + m)*K + k ----
    const int idx = blockIdx.x;
    const int k = idx % K_;
    const int b = idx / (N_ * M_ * K_);
    const size_t xbase = (((size_t)b * J_ + (J_ - 1)) * K_ + k) * (size_t)D_;
    const float4* __restrict__ x = (const float4*)(fmaps + xbase);
    const float4* __restrict__ v = (const float4*)(fmaps_neg + (size_t)idx * D_);

    float dot = 0.f, nv = 0.f, nx = 0.f;
#pragma unroll 4
    for (int i = threadIdx.x; i < D_ / 4; i += 256) {
      float4 a = x[i];
      float4 c = v[i];
      dot += a.x * c.x + a.y * c.y + a.z * c.z + a.w * c.w;
      nv  += c.x * c.x + c.y * c.y + c.z * c.z + c.w * c.w;
      nx  += a.x * a.x + a.y * a.y + a.z * a.z + a.w * a.w;
    }
    for (int off = 32; off > 0; off >>= 1) {
      dot += __shfl_down(dot, off, 64);
      nv  += __shfl_down(nv,  off, 64);
      nx  += __shfl_down(nx,  off, 64);
    }
    if (lane == 0) { s[0][wid] = dot; s[1][wid] = nv; s[2][wid] = nx; }
    __syncthreads();
    if (threadIdx.x == 0) {
      dot = s[0][0] + s[0][1] + s[0][2] + s[0][3];
      nv  = s[1][0] + s[1][1] + s[1][2] + s[1][3];
      nx  = s[2][0] + s[2][1] + s[2][2] + s[2][3];
      neg_out[idx] = dot / fmaxf(sqrtf(nx) * sqrtf(nv), EPS_) * TEMP_INV;
    }
  } else {
    // ---- positive logit: idx = b*K + k ----
    const int idx = blockIdx.x - NEG_BLOCKS;
    const int b = idx / K_, k = idx % K_;
    const size_t base = (((size_t)b * J_ + (J_ - 1)) * K_ + k) * (size_t)D_;
    const float4* __restrict__ x  = (const float4*)(fmaps + base);
    const float4* __restrict__ xp = (const float4*)(fmaps_pos + base);

    float dot = 0.f, nx = 0.f, np = 0.f;
#pragma unroll 4
    for (int i = threadIdx.x; i < D_ / 4; i += 256) {
      float4 a = x[i];
      float4 c = xp[i];
      dot += a.x * c.x + a.y * c.y + a.z * c.z + a.w * c.w;
      nx  += a.x * a.x + a.y * a.y + a.z * a.z + a.w * a.w;
      np  += c.x * c.x + c.y * c.y + c.z * c.z + c.w * c.w;
    }
    for (int off = 32; off > 0; off >>= 1) {
      dot += __shfl_down(dot, off, 64);
      nx  += __shfl_down(nx,  off, 64);
      np  += __shfl_down(np,  off, 64);
    }
    if (lane == 0) { s[0][wid] = dot; s[1][wid] = nx; s[2][wid] = np; }
    __syncthreads();
    if (threadIdx.x == 0) {
      dot = s[0][0] + s[0][1] + s[0][2] + s[0][3];
      nx  = s[1][0] + s[1][1] + s[1][2] + s[1][3];
      np  = s[2][0] + s[2][1] + s[2][2] + s[2][3];
      pos_out[idx] = dot / fmaxf(sqrtf(nx) * sqrtf(np), EPS_) * TEMP_INV;
    }
  }
}

// ---------------------------------------------------------------------------
// Kernel 2: masked logsumexp + final sum. Single block, one wave.
// ---------------------------------------------------------------------------
__global__ __launch_bounds__(64) void lse_kernel(
    const float* __restrict__ pos_in, const float* __restrict__ neg_in,
    const int* __restrict__ gt_labels, const int* __restrict__ gt_label_negs,
    float* __restrict__ out) {
  const int t = threadIdx.x;
  float contrib = 0.f;
  if (t < B_ * K_) {
    const int b = t / K_, k = t % K_;
    const int lbl = gt_labels[b * J_ + (J_ - 1)];
    const float p = pos_in[t];
    float mx = p;
    for (int i = 0; i < N_ * M_; ++i) {
      if (gt_label_negs[b * N_ * M_ + i] == lbl) {
        mx = fmaxf(mx, neg_in[((size_t)b * N_ * M_ + i) * K_ + k]);
      }
    }
    float ssum = expf(p - mx);
    for (int i = 0; i < N_ * M_; ++i) {
      if (gt_label_negs[b * N_ * M_ + i] == lbl) {
        ssum += expf(neg_in[((size_t)b * N_ * M_ + i) * K_ + k] - mx);
      }
    }
    contrib = (mx + logf(ssum)) - p;
  }
  for (int off = 32; off > 0; off >>= 1) contrib += __shfl_down(contrib, off, 64);
  if (t == 0) out[0] = contrib / (2.0f * (float)B_);
}

// ---------------------------------------------------------------------------
extern "C" void kernel_launch(void* const* d_in, const int* in_sizes, int n_in,
                              void* d_out, int out_size, void* d_ws, size_t ws_size,
                              hipStream_t stream) {
  const float* fmaps         = (const float*)d_in[0];
  const float* fmaps_pos     = (const float*)d_in[1];
  const float* fmaps_neg     = (const float*)d_in[2];
  const int*   gt_labels     = (const int*)d_in[3];
  const int*   gt_label_negs = (const int*)d_in[4];
  float* out = (float*)d_out;

  // workspace layout (floats): [0,24) pos logits | [24,24+1536) neg logits
  float* ws     = (float*)d_ws;
  float* pos_ws = ws;
  float* neg_ws = ws + POS_BLOCKS;

  logits_kernel<<<NEG_BLOCKS + POS_BLOCKS, 256, 0, stream>>>(
      fmaps, fmaps_pos, fmaps_neg, pos_ws, neg_ws);
  lse_kernel<<<1, 64, 0, stream>>>(pos_ws, neg_ws, gt_labels, gt_label_negs, out);
}